// Round 6
// baseline (1653.715 us; speedup 1.0000x reference)
//
#include <hip/hip_runtime.h>
#include <math.h>

#define B_    4096
#define N_    3400
#define NP_   3456          // N_ padded to 128
#define D1_   2048
#define D2_   1024
#define E_    10
#define NE_   (E_ * D2_)    // 10240 fused ensemble columns
#define C_    17
#define TOPK_ 20
#define TAU_  10.0f

typedef __bf16 bf16x8 __attribute__((ext_vector_type(8)));
typedef __bf16 bf16x4 __attribute__((ext_vector_type(4)));
typedef float  f32x4  __attribute__((ext_vector_type(4)));

__device__ inline float wsum64(float v){
  #pragma unroll
  for (int m = 1; m < 64; m <<= 1) v += __shfl_xor(v, m);
  return v;
}

__device__ __forceinline__ void gload_lds16(const unsigned short* g, unsigned short* l){
  __builtin_amdgcn_global_load_lds(
      (const __attribute__((address_space(1))) void*)g,
      (__attribute__((address_space(3))) void*)l, 16, 0, 0);
}

// --- row 1/max(||x||,eps) for [R][D] ---
__global__ __launch_bounds__(256)
void rownorm_inv(const float* __restrict__ X, int D, float* __restrict__ rinv){
  int r = blockIdx.x, t = threadIdx.x;
  const float4* x4 = reinterpret_cast<const float4*>(X + (long)r * D);
  float ss = 0.f;
  for (int i = t; i < (D >> 2); i += 256){
    float4 v = x4[i];
    ss += v.x*v.x + v.y*v.y + v.z*v.z + v.w*v.w;
  }
  __shared__ float red[256];
  red[t] = ss; __syncthreads();
  for (int s = 128; s; s >>= 1){ if (t < s) red[t] += red[t + s]; __syncthreads(); }
  if (t == 0) rinv[r] = 1.f / fmaxf(sqrtf(red[0]), 1e-12f);
}

__global__ void zero_cnt(float* cnt){ if (threadIdx.x < C_) cnt[threadIdx.x] = 0.f; }

__global__ __launch_bounds__(256)
void labelprep(const float* __restrict__ labels, int* __restrict__ y, float* __restrict__ cnt){
  int n = blockIdx.x * 256 + threadIdx.x;
  if (n >= N_) return;
  int c = 0;
  #pragma unroll
  for (int cc = 0; cc < C_; ++cc) if (labels[n * C_ + cc] > 0.5f) c = cc;
  y[n] = c;
  atomicAdd(&cnt[c], 1.0f);
}

// fp32 -> (hi bf16, lo bf16 of exact residual), 4 elems/thread
__global__ __launch_bounds__(256)
void cvt_split(const float* __restrict__ src, unsigned short* __restrict__ hi,
               unsigned short* __restrict__ lo, long n4){
  long i = (long)blockIdx.x * 256 + threadIdx.x;
  if (i >= n4) return;
  float4 v = reinterpret_cast<const float4*>(src)[i];
  float f[4] = {v.x, v.y, v.z, v.w};
  bf16x4 h4, l4;
  #pragma unroll
  for (int j = 0; j < 4; ++j){
    __bf16 h = (__bf16)f[j];
    h4[j] = h;
    l4[j] = (__bf16)(f[j] - (float)h);
  }
  reinterpret_cast<bf16x4*>(hi)[i] = h4;
  reinterpret_cast<bf16x4*>(lo)[i] = l4;
}

// zero-fill pad rows [N_, NP_) of two bf16 [NP_][D1_] arrays (16B stores)
__global__ __launch_bounds__(256)
void fill_pad(unsigned short* __restrict__ a, unsigned short* __restrict__ b){
  int i = blockIdx.x * 256 + threadIdx.x;   // 16B units; total (NP_-N_)*D1_/8 = 14336
  uint4 zz = make_uint4(0,0,0,0);
  reinterpret_cast<uint4*>(a + (long)N_ * D1_)[i] = zz;
  reinterpret_cast<uint4*>(b + (long)N_ * D1_)[i] = zz;
}

// Wbf[e][n][k] = bf16(alpha[e][k] * W[n][k]),  laid out [NE_][D1_]
__global__ __launch_bounds__(256)
void wfold(const float* __restrict__ W, const float* __restrict__ alpha,
           unsigned short* __restrict__ wbf){
  long i = (long)blockIdx.x * 256 + threadIdx.x;       // float4 units
  const long perE = (long)D2_ * D1_ / 4;               // 524288
  int e = (int)(i / perE);
  long r = i - (long)e * perE;
  int k4 = (int)(r & (D1_/4 - 1));
  float4 wv = reinterpret_cast<const float4*>(W)[r];
  float4 av = reinterpret_cast<const float4*>(alpha + (long)e * D1_)[k4];
  bf16x4 o;
  o[0] = (__bf16)(wv.x * av.x);
  o[1] = (__bf16)(wv.y * av.y);
  o[2] = (__bf16)(wv.z * av.z);
  o[3] = (__bf16)(wv.w * av.w);
  reinterpret_cast<bf16x4*>(wbf)[i] = o;
}

// Fused BatchEnsemble GEMM, bf16 inputs, double-buffered global_load_lds (T3 2-phase).
// A [Mpad][D1_] bf16, Bw [NE_][D1_] bf16 (alpha-folded W).
// Out[e][m][ncol] = acc * gamma[n'] + bias[n'],  n' = e*1024+ncol.
__global__ __launch_bounds__(256)
void mfma_be(const unsigned short* __restrict__ A,
             const unsigned short* __restrict__ Bw,
             const float* __restrict__ gamma,   // [NE_]
             const float* __restrict__ bias,    // [NE_]
             float* __restrict__ Out, long estride, int M)
{
  __shared__ unsigned short Alds[2][128 * 32];
  __shared__ unsigned short Blds[2][128 * 32];
  const int n0 = blockIdx.x * 128;
  const int m0 = blockIdx.y * 128;
  const int t  = threadIdx.x;
  const int lane = t & 63;
  const int w  = t >> 6;
  const int wr = w >> 1, wc = w & 1;
  const int r15 = lane & 15, kb = lane >> 4;

  // wave w stages subtiles {2w, 2w+1}; lane l -> row (l&15), k-block (l>>4)
  const unsigned short* ga0 = A  + (long)(m0 + 32*w      + r15) * D1_ + kb * 8;
  const unsigned short* ga1 = A  + (long)(m0 + 32*w + 16 + r15) * D1_ + kb * 8;
  const unsigned short* gb0 = Bw + (long)(n0 + 32*w      + r15) * D1_ + kb * 8;
  const unsigned short* gb1 = Bw + (long)(n0 + 32*w + 16 + r15) * D1_ + kb * 8;
  const unsigned so0 = (2*w) * 512, so1 = (2*w+1) * 512;

  f32x4 acc[4][4];
  #pragma unroll
  for (int i = 0; i < 4; ++i)
    #pragma unroll
    for (int j = 0; j < 4; ++j)
      acc[i][j] = (f32x4){0.f, 0.f, 0.f, 0.f};

  auto stage = [&](int buf, int k0){
    gload_lds16(ga0 + k0, &Alds[buf][so0]);
    gload_lds16(ga1 + k0, &Alds[buf][so1]);
    gload_lds16(gb0 + k0, &Blds[buf][so0]);
    gload_lds16(gb1 + k0, &Blds[buf][so1]);
  };

  stage(0, 0);
  __syncthreads();                       // drain buf0
  for (int tt = 0; tt < 64; ++tt){
    const int cur = tt & 1;
    if (tt < 63) stage(cur ^ 1, (tt + 1) * 32);   // prefetch next tile

    bf16x8 af[4], bfv[4];
    #pragma unroll
    for (int i = 0; i < 4; ++i)
      af[i] = *reinterpret_cast<const bf16x8*>(&Alds[cur][(wr*4 + i) * 512 + lane * 8]);
    #pragma unroll
    for (int j = 0; j < 4; ++j)
      bfv[j] = *reinterpret_cast<const bf16x8*>(&Blds[cur][(wc*4 + j) * 512 + lane * 8]);
    #pragma unroll
    for (int i = 0; i < 4; ++i)
      #pragma unroll
      for (int j = 0; j < 4; ++j)
        acc[i][j] = __builtin_amdgcn_mfma_f32_16x16x32_bf16(af[i], bfv[j], acc[i][j], 0, 0, 0);

    __syncthreads();                     // drain prefetch + ds reads once per K-step
  }

  const int mb = m0 + wr * 64 + (lane >> 4) * 4;
  const int nbase = n0 + wc * 64 + (lane & 15);
  #pragma unroll
  for (int j = 0; j < 4; ++j){
    int n = nbase + j * 16;            // fused column in [0, NE_)
    int e = n >> 10, ncol = n & 1023;
    float g = gamma[n], o = bias[n];
    float* op = Out + (long)e * estride;
    #pragma unroll
    for (int i = 0; i < 4; ++i){
      #pragma unroll
      for (int r = 0; r < 4; ++r){
        int m = mb + i * 16 + r;
        if (m < M) op[(long)m * D2_ + ncol] = acc[i][j][r] * g + o;
      }
    }
  }
}

// scores[m][n] = zinv[m]*sinv[n]*(Z·S), split-bf16 3-term as a flat 3-segment GEMM:
// segments (zh,sh),(zh,sl),(zl,sh) over K'=3*2048, double-buffered gload_lds.
__global__ __launch_bounds__(256)
void mfma_scores2(const unsigned short* __restrict__ zh, const unsigned short* __restrict__ zl,
                  const unsigned short* __restrict__ sh, const unsigned short* __restrict__ sl,
                  const float* __restrict__ zinv, const float* __restrict__ sinv,
                  float* __restrict__ Out)
{
  __shared__ unsigned short Albuf[2][128 * 32];
  __shared__ unsigned short Blbuf[2][128 * 32];
  const int n0 = blockIdx.x * 128;
  const int m0 = blockIdx.y * 128;
  const int t  = threadIdx.x;
  const int lane = t & 63;
  const int w  = t >> 6;
  const int wr = w >> 1, wc = w & 1;
  const int r15 = lane & 15, kb = lane >> 4;

  const long arow0 = (long)(m0 + 32*w      + r15) * D1_ + kb * 8;
  const long arow1 = (long)(m0 + 32*w + 16 + r15) * D1_ + kb * 8;
  const long brow0 = (long)(n0 + 32*w      + r15) * D1_ + kb * 8;
  const long brow1 = (long)(n0 + 32*w + 16 + r15) * D1_ + kb * 8;
  const unsigned so0 = (2*w) * 512, so1 = (2*w+1) * 512;

  f32x4 acc[4][4];
  #pragma unroll
  for (int i = 0; i < 4; ++i)
    #pragma unroll
    for (int j = 0; j < 4; ++j)
      acc[i][j] = (f32x4){0.f, 0.f, 0.f, 0.f};

  auto stage = [&](int buf, int it){
    // seg 0: zh*sh   seg 1: zh*sl   seg 2: zl*sh
    const unsigned short* ap = (it >= 128) ? zl : zh;
    const unsigned short* bp = ((it >> 6) == 1) ? sl : sh;
    const int k0 = (it & 63) * 32;
    gload_lds16(ap + arow0 + k0, &Albuf[buf][so0]);
    gload_lds16(ap + arow1 + k0, &Albuf[buf][so1]);
    gload_lds16(bp + brow0 + k0, &Blbuf[buf][so0]);
    gload_lds16(bp + brow1 + k0, &Blbuf[buf][so1]);
  };

  stage(0, 0);
  __syncthreads();
  for (int it = 0; it < 192; ++it){
    const int cur = it & 1;
    if (it < 191) stage(cur ^ 1, it + 1);

    bf16x8 af[4], bfv[4];
    #pragma unroll
    for (int i = 0; i < 4; ++i)
      af[i] = *reinterpret_cast<const bf16x8*>(&Albuf[cur][(wr*4 + i) * 512 + lane * 8]);
    #pragma unroll
    for (int j = 0; j < 4; ++j)
      bfv[j] = *reinterpret_cast<const bf16x8*>(&Blbuf[cur][(wc*4 + j) * 512 + lane * 8]);
    #pragma unroll
    for (int i = 0; i < 4; ++i)
      #pragma unroll
      for (int j = 0; j < 4; ++j)
        acc[i][j] = __builtin_amdgcn_mfma_f32_16x16x32_bf16(af[i], bfv[j], acc[i][j], 0, 0, 0);

    __syncthreads();
  }

  const int mb = m0 + wr * 64 + (lane >> 4) * 4;
  const int nb = n0 + wc * 64 + (lane & 15);
  #pragma unroll
  for (int j = 0; j < 4; ++j){
    int n = nb + j * 16;
    if (n >= N_) continue;
    float si = sinv[n];
    #pragma unroll
    for (int i = 0; i < 4; ++i){
      #pragma unroll
      for (int r = 0; r < 4; ++r){
        int m = mb + i * 16 + r;
        Out[(long)m * N_ + n] = acc[i][j][r] * zinv[m] * si;
      }
    }
  }
}

// top-20 (value desc, tie -> lower index) per row of scores[B_][N_]
__global__ __launch_bounds__(256)
void topk20(const float* __restrict__ scores, int* __restrict__ idx){
  __shared__ float v[N_];
  __shared__ float rv[256];
  __shared__ int   ri[256];
  const int b = blockIdx.x, t = threadIdx.x;
  const float* row = scores + (long)b * N_;
  for (int i = t; i < N_; i += 256) v[i] = row[i];
  __syncthreads();
  for (int it = 0; it < TOPK_; ++it){
    float bv = -3.0e38f; int bi = 0x7fffffff;
    for (int i = t; i < N_; i += 256){
      float x = v[i];
      if (x > bv){ bv = x; bi = i; }
    }
    rv[t] = bv; ri[t] = bi; __syncthreads();
    for (int s = 128; s; s >>= 1){
      if (t < s){
        float ov = rv[t + s]; int oi = ri[t + s];
        if (ov > rv[t] || (ov == rv[t] && oi < ri[t])){ rv[t] = ov; ri[t] = oi; }
      }
      __syncthreads();
    }
    if (t == 0){ idx[b * TOPK_ + it] = ri[0]; v[ri[0]] = -3.0e38f; }
    __syncthreads();
  }
}

__global__ __launch_bounds__(256)
void centroid_part(const float* __restrict__ mlps, const int* __restrict__ y,
                   const float* __restrict__ cnt, float* __restrict__ part){
  __shared__ float acc[C_ * 256];
  __shared__ float winv[C_];
  const int t  = threadIdx.x;
  const int ob = blockIdx.x * 256;
  const int e  = blockIdx.y;
  const int s  = blockIdx.z;
  #pragma unroll
  for (int c = 0; c < C_; ++c) acc[c * 256 + t] = 0.f;
  if (t < C_) winv[t] = 1.f / (cnt[t] + 1e-12f);
  __syncthreads();
  const int n0 = s * 425, n1 = n0 + 425;
  for (int n = n0; n < n1; ++n){
    int c = y[n];
    float v = mlps[((long)e * N_ + n) * D2_ + ob + t];
    acc[c * 256 + t] += winv[c] * v;
  }
  #pragma unroll
  for (int c = 0; c < C_; ++c)
    part[(((long)s * E_ + e) * C_ + c) * D2_ + ob + t] = acc[c * 256 + t];
}

__global__ __launch_bounds__(256)
void centroid_reduce(const float* __restrict__ part, float* __restrict__ cent){
  int i = blockIdx.x * 256 + threadIdx.x;
  if (i >= E_ * C_ * D2_) return;
  float s = 0.f;
  #pragma unroll
  for (int k = 0; k < 8; ++k) s += part[(long)k * E_ * C_ * D2_ + i];
  cent[i] = s;
}

__global__ __launch_bounds__(256)
void rownorm_inplace(float* __restrict__ X, int D){
  int r = blockIdx.x, t = threadIdx.x;
  float4* x4 = reinterpret_cast<float4*>(X + (long)r * D);
  float ss = 0.f;
  for (int i = t; i < (D >> 2); i += 256){
    float4 v = x4[i];
    ss += v.x*v.x + v.y*v.y + v.z*v.z + v.w*v.w;
  }
  __shared__ float red[256];
  red[t] = ss; __syncthreads();
  for (int s2 = 128; s2; s2 >>= 1){ if (t < s2) red[t] += red[t + s2]; __syncthreads(); }
  float rinv = 1.f / fmaxf(sqrtf(red[0]), 1e-12f);
  for (int i = t; i < (D >> 2); i += 256){
    float4 v = x4[i];
    v.x *= rinv; v.y *= rinv; v.z *= rinv; v.w *= rinv;
    x4[i] = v;
  }
}

// per (e,row): 17 cosine dots with cn; mode 1 -> softmax, mode 0 -> TAU*cos
// 4 waves/block, one row per wave
__global__ __launch_bounds__(256)
void ens_dot(const float* __restrict__ mlp, const float* __restrict__ cn,
             float* __restrict__ out, int mlp_rows, int out_M, int out_rowoff, int mode){
  const int wv = threadIdx.x >> 6, l = threadIdx.x & 63;
  const int row = blockIdx.x * 4 + wv, e = blockIdx.y;
  if (row >= mlp_rows) return;
  const float4* r4 = reinterpret_cast<const float4*>(mlp + ((long)e * mlp_rows + row) * D2_);
  float4 r[4];
  #pragma unroll
  for (int j = 0; j < 4; ++j) r[j] = r4[j * 64 + l];
  float ss = 0.f;
  #pragma unroll
  for (int j = 0; j < 4; ++j) ss += r[j].x*r[j].x + r[j].y*r[j].y + r[j].z*r[j].z + r[j].w*r[j].w;
  ss = wsum64(ss);
  float rinv = 1.f / fmaxf(sqrtf(ss), 1e-12f);
  float tv[C_];
  #pragma unroll
  for (int c = 0; c < C_; ++c){
    const float4* c4 = reinterpret_cast<const float4*>(cn + ((long)e * C_ + c) * D2_);
    float p = 0.f;
    #pragma unroll
    for (int j = 0; j < 4; ++j){
      float4 cv = c4[j * 64 + l];
      p += r[j].x*cv.x + r[j].y*cv.y + r[j].z*cv.z + r[j].w*cv.w;
    }
    tv[c] = wsum64(p) * rinv * TAU_;
  }
  long obase = ((long)e * out_M + out_rowoff + row) * C_;
  if (mode == 0){
    if (l == 0){
      #pragma unroll
      for (int c = 0; c < C_; ++c) out[obase + c] = tv[c];
    }
  } else {
    float m = tv[0];
    #pragma unroll
    for (int c = 1; c < C_; ++c) m = fmaxf(m, tv[c]);
    float p[C_]; float sum = 0.f;
    #pragma unroll
    for (int c = 0; c < C_; ++c){ p[c] = expf(tv[c] - m); sum += p[c]; }
    float is = 1.f / sum;
    if (l == 0){
      #pragma unroll
      for (int c = 0; c < C_; ++c) out[obase + c] = p[c] * is;
    }
  }
}

__global__ __launch_bounds__(256)
void outputs_k(const float* __restrict__ soft, const int* __restrict__ idx, float* __restrict__ out){
  const int lane = threadIdx.x & 63;
  const int b = blockIdx.x * 4 + (threadIdx.x >> 6);
  const int* id = idx + b * TOPK_;
  float o = 0.f;
  for (int e = 0; e < E_; ++e){
    float S = 0.f;
    const float* se = soft + (long)e * N_ * C_;
    #pragma unroll
    for (int k = 0; k < TOPK_; ++k){
      int n = id[k];
      if (lane < C_) S += se[(long)n * C_ + lane];
    }
    float tot = wsum64(S);
    o += S / (tot + 1e-12f);
  }
  if (lane < C_) out[(long)b * C_ + lane] = o * (1.f / E_);
}

extern "C" void kernel_launch(void* const* d_in, const int* in_sizes, int n_in,
                              void* d_out, int out_size, void* d_ws, size_t ws_size,
                              hipStream_t stream){
  const float* z        = (const float*)d_in[0];
  const float* supports = (const float*)d_in[1];
  const float* labels   = (const float*)d_in[2];
  const float* weight   = (const float*)d_in[3];
  const float* alpha    = (const float*)d_in[4];
  const float* gamma    = (const float*)d_in[5];
  const float* bias     = (const float*)d_in[6];
  float* out = (float*)d_out;

  char* w = (char*)d_ws;
  size_t off = 0;
  auto alloc = [&](size_t bytes)->char*{
    char* p = w + off;
    off = (off + bytes + 255) & ~(size_t)255;
    return p;
  };
  auto rup = [](size_t b)->size_t{ return (b + 255) & ~(size_t)255; };

  // ---- permanent region (~82 MB) ----
  float* zinv   = (float*)alloc((size_t)B_ * 4);
  float* sinv   = (float*)alloc((size_t)N_ * 4);
  float* cnt    = (float*)alloc((size_t)C_ * 4);
  int*   y      = (int*)  alloc((size_t)N_ * 4);
  int*   idx    = (int*)  alloc((size_t)B_ * TOPK_ * 4);
  unsigned short* zh  = (unsigned short*)alloc((size_t)B_  * D1_ * 2);
  unsigned short* sh  = (unsigned short*)alloc((size_t)NP_ * D1_ * 2);
  unsigned short* wbf = (unsigned short*)alloc((size_t)NE_ * D1_ * 2);
  float* cent = (float*)alloc((size_t)E_ * C_ * D2_ * 4);
  float* part = (float*)alloc((size_t)8 * E_ * C_ * D2_ * 4);
  float* soft = (float*)alloc((size_t)E_ * N_ * C_ * 4);

  // ---- overlay region: lifetimes do not overlap (≈139 MB) ----
  const size_t scores_b = (size_t)B_ * N_ * 4;
  const size_t zl_b     = (size_t)B_  * D1_ * 2;
  const size_t sl_b     = (size_t)NP_ * D1_ * 2;
  const size_t mlps_b   = (size_t)E_ * N_ * D2_ * 4;
  size_t ph1 = rup(scores_b) + rup(zl_b) + rup(sl_b);
  char* overlay = alloc(ph1 > mlps_b ? ph1 : mlps_b);
  float*          scores = (float*)overlay;
  unsigned short* zl     = (unsigned short*)(overlay + rup(scores_b));
  unsigned short* sl     = (unsigned short*)(overlay + rup(scores_b) + rup(zl_b));
  float*          mlps   = (float*)overlay;          // after topk20
  float*          mlpz   = (float*)overlay;          // after ens_dot(soft)
  (void)ws_size; (void)in_sizes; (void)n_in; (void)out_size;

  // row norms + label prep
  rownorm_inv<<<B_, 256, 0, stream>>>(z, D1_, zinv);
  rownorm_inv<<<N_, 256, 0, stream>>>(supports, D1_, sinv);
  zero_cnt<<<1, 32, 0, stream>>>(cnt);
  labelprep<<<(N_ + 255) / 256, 256, 0, stream>>>(labels, y, cnt);

  // bf16 precompute: hi/lo splits (hi doubles as the mlp A operand), pad, folded W
  cvt_split<<<(B_ * D1_ / 4 + 255) / 256, 256, 0, stream>>>(z, zh, zl, (long)B_ * D1_ / 4);
  cvt_split<<<(N_ * D1_ / 4 + 255) / 256, 256, 0, stream>>>(supports, sh, sl, (long)N_ * D1_ / 4);
  fill_pad<<<(NP_ - N_) * D1_ / 8 / 256, 256, 0, stream>>>(sh, sl);
  wfold<<<(int)((long)NE_ * D1_ / 4 / 256), 256, 0, stream>>>(weight, alpha, wbf);

  // cosine scores (split-bf16 3-term, fp32-faithful for top-k) + top-20
  mfma_scores2<<<dim3(NP_ / 128, B_ / 128, 1), 256, 0, stream>>>(
      zh, zl, sh, sl, zinv, sinv, scores);
  topk20<<<B_, 256, 0, stream>>>(scores, idx);
  // (scores, zl, sl dead from here)

  // mlp_s: single fused GEMM over N' = E*D2 columns
  mfma_be<<<dim3(NE_ / 128, NP_ / 128, 1), 256, 0, stream>>>(
      sh, wbf, gamma, bias, mlps, (long)N_ * D2_, N_);

  // centroids, then L2-normalize rows
  centroid_part<<<dim3(D2_ / 256, E_, 8), 256, 0, stream>>>(mlps, y, cnt, part);
  centroid_reduce<<<(E_ * C_ * D2_ + 255) / 256, 256, 0, stream>>>(part, cent);
  rownorm_inplace<<<E_ * C_, 256, 0, stream>>>(cent, D2_);

  // soft = softmax(TAU * cos(mlp_s, cent))
  ens_dot<<<dim3((N_ + 3) / 4, E_), 256, 0, stream>>>(mlps, cent, soft, N_, N_, 0, 1);

  // outputs
  outputs_k<<<B_ / 4, 256, 0, stream>>>(soft, idx, out);
  // (mlps dead from here; mlpz reuses its space)

  // logits, chunked over z rows
  float* logits = out + (size_t)B_ * C_;
  for (int ch = 0; ch < 4; ++ch){
    mfma_be<<<dim3(NE_ / 128, 1024 / 128, 1), 256, 0, stream>>>(
        zh + (size_t)ch * 1024 * D1_, wbf, gamma, bias, mlpz, (long)1024 * D2_, 1024);
    ens_dot<<<dim3(1024 / 4, E_), 256, 0, stream>>>(mlpz, cent, logits, 1024, B_, ch * 1024, 0);
  }
}

// Round 7
// 1365.607 us; speedup vs baseline: 1.2110x; 1.2110x over previous
//
#include <hip/hip_runtime.h>
#include <math.h>

#define B_    4096
#define N_    3400
#define NP_   3456          // N_ padded to 128
#define D1_   2048
#define D2_   1024
#define E_    10
#define NE_   (E_ * D2_)    // 10240 fused ensemble columns
#define C_    17
#define TOPK_ 20
#define TAU_  10.0f

typedef __bf16 bf16x8 __attribute__((ext_vector_type(8)));
typedef __bf16 bf16x4 __attribute__((ext_vector_type(4)));
typedef float  f32x4  __attribute__((ext_vector_type(4)));

__device__ inline float wsum64(float v){
  #pragma unroll
  for (int m = 1; m < 64; m <<= 1) v += __shfl_xor(v, m);
  return v;
}

__device__ __forceinline__ void gload_lds16(const unsigned short* g, unsigned short* l){
  __builtin_amdgcn_global_load_lds(
      (const __attribute__((address_space(1))) void*)g,
      (__attribute__((address_space(3))) void*)l, 16, 0, 0);
}

// --- row 1/max(||x||,eps) for [R][D] ---
__global__ __launch_bounds__(256)
void rownorm_inv(const float* __restrict__ X, int D, float* __restrict__ rinv){
  int r = blockIdx.x, t = threadIdx.x;
  const float4* x4 = reinterpret_cast<const float4*>(X + (long)r * D);
  float ss = 0.f;
  for (int i = t; i < (D >> 2); i += 256){
    float4 v = x4[i];
    ss += v.x*v.x + v.y*v.y + v.z*v.z + v.w*v.w;
  }
  __shared__ float red[256];
  red[t] = ss; __syncthreads();
  for (int s = 128; s; s >>= 1){ if (t < s) red[t] += red[t + s]; __syncthreads(); }
  if (t == 0) rinv[r] = 1.f / fmaxf(sqrtf(red[0]), 1e-12f);
}

__global__ void zero_cnt(float* cnt){ if (threadIdx.x < C_) cnt[threadIdx.x] = 0.f; }

__global__ __launch_bounds__(256)
void labelprep(const float* __restrict__ labels, int* __restrict__ y, float* __restrict__ cnt){
  int n = blockIdx.x * 256 + threadIdx.x;
  if (n >= N_) return;
  int c = 0;
  #pragma unroll
  for (int cc = 0; cc < C_; ++cc) if (labels[n * C_ + cc] > 0.5f) c = cc;
  y[n] = c;
  atomicAdd(&cnt[c], 1.0f);
}

// fp32 -> (hi bf16, lo bf16 of exact residual), 4 elems/thread
__global__ __launch_bounds__(256)
void cvt_split(const float* __restrict__ src, unsigned short* __restrict__ hi,
               unsigned short* __restrict__ lo, long n4){
  long i = (long)blockIdx.x * 256 + threadIdx.x;
  if (i >= n4) return;
  float4 v = reinterpret_cast<const float4*>(src)[i];
  float f[4] = {v.x, v.y, v.z, v.w};
  bf16x4 h4, l4;
  #pragma unroll
  for (int j = 0; j < 4; ++j){
    __bf16 h = (__bf16)f[j];
    h4[j] = h;
    l4[j] = (__bf16)(f[j] - (float)h);
  }
  reinterpret_cast<bf16x4*>(hi)[i] = h4;
  reinterpret_cast<bf16x4*>(lo)[i] = l4;
}

// zero-fill pad rows [N_, NP_) of two bf16 [NP_][D1_] arrays (16B stores)
__global__ __launch_bounds__(256)
void fill_pad(unsigned short* __restrict__ a, unsigned short* __restrict__ b){
  int i = blockIdx.x * 256 + threadIdx.x;   // 16B units; total (NP_-N_)*D1_/8 = 14336
  uint4 zz = make_uint4(0,0,0,0);
  reinterpret_cast<uint4*>(a + (long)N_ * D1_)[i] = zz;
  reinterpret_cast<uint4*>(b + (long)N_ * D1_)[i] = zz;
}

// Wbf[e][n][k] = bf16(alpha[e][k] * W[n][k]),  laid out [NE_][D1_]
__global__ __launch_bounds__(256)
void wfold(const float* __restrict__ W, const float* __restrict__ alpha,
           unsigned short* __restrict__ wbf){
  long i = (long)blockIdx.x * 256 + threadIdx.x;       // float4 units
  const long perE = (long)D2_ * D1_ / 4;               // 524288
  int e = (int)(i / perE);
  long r = i - (long)e * perE;
  int k4 = (int)(r & (D1_/4 - 1));
  float4 wv = reinterpret_cast<const float4*>(W)[r];
  float4 av = reinterpret_cast<const float4*>(alpha + (long)e * D1_)[k4];
  bf16x4 o;
  o[0] = (__bf16)(wv.x * av.x);
  o[1] = (__bf16)(wv.y * av.y);
  o[2] = (__bf16)(wv.z * av.z);
  o[3] = (__bf16)(wv.w * av.w);
  reinterpret_cast<bf16x4*>(wbf)[i] = o;
}

// Fused BatchEnsemble GEMM, bf16 inputs, global_load_lds staging (R5 known-good).
// Out[e][m][ncol] = acc * gamma[n'] + bias[n'],  n' = e*1024+ncol.
__global__ __launch_bounds__(256)
void mfma_be(const unsigned short* __restrict__ A,
             const unsigned short* __restrict__ Bw,
             const float* __restrict__ gamma,   // [NE_]
             const float* __restrict__ bias,    // [NE_]
             float* __restrict__ Out, long estride, int M)
{
  __shared__ unsigned short Alds[128 * 32];
  __shared__ unsigned short Blds[128 * 32];
  const int n0 = blockIdx.x * 128;
  const int m0 = blockIdx.y * 128;
  const int t  = threadIdx.x;
  const int lane = t & 63;
  const int w  = t >> 6;
  const int wr = w >> 1, wc = w & 1;
  const int r15 = lane & 15, kb = lane >> 4;

  // wave w stages subtiles {2w, 2w+1}; lane l -> row (l&15), k-block (l>>4)
  const unsigned short* ga0 = A  + (long)(m0 + 32*w      + r15) * D1_ + kb * 8;
  const unsigned short* ga1 = A  + (long)(m0 + 32*w + 16 + r15) * D1_ + kb * 8;
  const unsigned short* gb0 = Bw + (long)(n0 + 32*w      + r15) * D1_ + kb * 8;
  const unsigned short* gb1 = Bw + (long)(n0 + 32*w + 16 + r15) * D1_ + kb * 8;
  unsigned short* la0 = &Alds[(2*w)   * 512];
  unsigned short* la1 = &Alds[(2*w+1) * 512];
  unsigned short* lb0 = &Blds[(2*w)   * 512];
  unsigned short* lb1 = &Blds[(2*w+1) * 512];

  f32x4 acc[4][4];
  #pragma unroll
  for (int i = 0; i < 4; ++i)
    #pragma unroll
    for (int j = 0; j < 4; ++j)
      acc[i][j] = (f32x4){0.f, 0.f, 0.f, 0.f};

  for (int k0 = 0; k0 < D1_; k0 += 32){
    __syncthreads();                   // prior ds_reads done before overwrite
    gload_lds16(ga0 + k0, la0);
    gload_lds16(ga1 + k0, la1);
    gload_lds16(gb0 + k0, lb0);
    gload_lds16(gb1 + k0, lb1);
    __syncthreads();                   // vmcnt(0) drain before reads

    bf16x8 af[4], bfv[4];
    #pragma unroll
    for (int i = 0; i < 4; ++i)
      af[i] = *reinterpret_cast<const bf16x8*>(&Alds[(wr*4 + i) * 512 + lane * 8]);
    #pragma unroll
    for (int j = 0; j < 4; ++j)
      bfv[j] = *reinterpret_cast<const bf16x8*>(&Blds[(wc*4 + j) * 512 + lane * 8]);
    #pragma unroll
    for (int i = 0; i < 4; ++i)
      #pragma unroll
      for (int j = 0; j < 4; ++j)
        acc[i][j] = __builtin_amdgcn_mfma_f32_16x16x32_bf16(af[i], bfv[j], acc[i][j], 0, 0, 0);
  }

  const int mb = m0 + wr * 64 + (lane >> 4) * 4;
  const int nbase = n0 + wc * 64 + (lane & 15);
  #pragma unroll
  for (int j = 0; j < 4; ++j){
    int n = nbase + j * 16;            // fused column in [0, NE_)
    int e = n >> 10, ncol = n & 1023;
    float g = gamma[n], o = bias[n];
    float* op = Out + (long)e * estride;
    #pragma unroll
    for (int i = 0; i < 4; ++i){
      #pragma unroll
      for (int r = 0; r < 4; ++r){
        int m = mb + i * 16 + r;
        if (m < M) op[(long)m * D2_ + ncol] = acc[i][j][r] * g + o;
      }
    }
  }
}

// scores[m][n] = zinv[m]*sinv[n]*(Z·S) via split-bf16 3-term MFMA (R5 known-good)
__global__ __launch_bounds__(256)
void mfma_scores2(const unsigned short* __restrict__ zh, const unsigned short* __restrict__ zl,
                  const unsigned short* __restrict__ sh, const unsigned short* __restrict__ sl,
                  const float* __restrict__ zinv, const float* __restrict__ sinv,
                  float* __restrict__ Out)
{
  __shared__ unsigned short Ah[128 * 32];
  __shared__ unsigned short Al[128 * 32];
  __shared__ unsigned short Bh[128 * 32];
  __shared__ unsigned short Bl[128 * 32];
  const int n0 = blockIdx.x * 128;
  const int m0 = blockIdx.y * 128;
  const int t  = threadIdx.x;
  const int lane = t & 63;
  const int w  = t >> 6;
  const int wr = w >> 1, wc = w & 1;
  const int r15 = lane & 15, kb = lane >> 4;

  const long arow0 = (long)(m0 + 32*w      + r15) * D1_ + kb * 8;
  const long arow1 = (long)(m0 + 32*w + 16 + r15) * D1_ + kb * 8;
  const long brow0 = (long)(n0 + 32*w      + r15) * D1_ + kb * 8;
  const long brow1 = (long)(n0 + 32*w + 16 + r15) * D1_ + kb * 8;
  const unsigned s0 = (2*w) * 512, s1 = (2*w+1) * 512;

  f32x4 acc[4][4];
  #pragma unroll
  for (int i = 0; i < 4; ++i)
    #pragma unroll
    for (int j = 0; j < 4; ++j)
      acc[i][j] = (f32x4){0.f, 0.f, 0.f, 0.f};

  for (int k0 = 0; k0 < D1_; k0 += 32){
    __syncthreads();
    gload_lds16(zh + arow0 + k0, &Ah[s0]);
    gload_lds16(zh + arow1 + k0, &Ah[s1]);
    gload_lds16(zl + arow0 + k0, &Al[s0]);
    gload_lds16(zl + arow1 + k0, &Al[s1]);
    gload_lds16(sh + brow0 + k0, &Bh[s0]);
    gload_lds16(sh + brow1 + k0, &Bh[s1]);
    gload_lds16(sl + brow0 + k0, &Bl[s0]);
    gload_lds16(sl + brow1 + k0, &Bl[s1]);
    __syncthreads();

    bf16x8 afh[4], bfh[4];
    #pragma unroll
    for (int i = 0; i < 4; ++i)
      afh[i] = *reinterpret_cast<const bf16x8*>(&Ah[(wr*4 + i) * 512 + lane * 8]);
    #pragma unroll
    for (int j = 0; j < 4; ++j)
      bfh[j] = *reinterpret_cast<const bf16x8*>(&Bh[(wc*4 + j) * 512 + lane * 8]);
    #pragma unroll
    for (int i = 0; i < 4; ++i)
      #pragma unroll
      for (int j = 0; j < 4; ++j)
        acc[i][j] = __builtin_amdgcn_mfma_f32_16x16x32_bf16(afh[i], bfh[j], acc[i][j], 0, 0, 0);

    bf16x8 bfl[4];
    #pragma unroll
    for (int j = 0; j < 4; ++j)
      bfl[j] = *reinterpret_cast<const bf16x8*>(&Bl[(wc*4 + j) * 512 + lane * 8]);
    #pragma unroll
    for (int i = 0; i < 4; ++i)
      #pragma unroll
      for (int j = 0; j < 4; ++j)
        acc[i][j] = __builtin_amdgcn_mfma_f32_16x16x32_bf16(afh[i], bfl[j], acc[i][j], 0, 0, 0);

    bf16x8 afl[4];
    #pragma unroll
    for (int i = 0; i < 4; ++i)
      afl[i] = *reinterpret_cast<const bf16x8*>(&Al[(wr*4 + i) * 512 + lane * 8]);
    #pragma unroll
    for (int i = 0; i < 4; ++i)
      #pragma unroll
      for (int j = 0; j < 4; ++j)
        acc[i][j] = __builtin_amdgcn_mfma_f32_16x16x32_bf16(afl[i], bfh[j], acc[i][j], 0, 0, 0);
  }

  const int mb = m0 + wr * 64 + (lane >> 4) * 4;
  const int nb = n0 + wc * 64 + (lane & 15);
  #pragma unroll
  for (int j = 0; j < 4; ++j){
    int n = nb + j * 16;
    if (n >= N_) continue;
    float si = sinv[n];
    #pragma unroll
    for (int i = 0; i < 4; ++i){
      #pragma unroll
      for (int r = 0; r < 4; ++r){
        int m = mb + i * 16 + r;
        Out[(long)m * N_ + n] = acc[i][j][r] * zinv[m] * si;
      }
    }
  }
}

// register-resident top-20 (value desc, tie -> lower index) per row of scores[B_][N_]
// thread t owns elements {t + 256j, j=0..13} in registers; per pick: unrolled local
// max -> 6-step shfl_xor butterfly -> 4-entry LDS cross-wave merge -> predicated clear.
__global__ __launch_bounds__(256)
void topk20(const float* __restrict__ scores, int* __restrict__ idx){
  const int b = blockIdx.x, t = threadIdx.x;
  const int l = t & 63, wid = t >> 6;
  const float* row = scores + (long)b * N_;
  float v[14];
  #pragma unroll
  for (int j = 0; j < 14; ++j){
    int i = t + j * 256;
    v[j] = (i < N_) ? row[i] : -3.0e38f;
  }
  __shared__ float wv[4];
  __shared__ int   wi[4];
  for (int it = 0; it < TOPK_; ++it){
    float bv = -3.0e38f; int bj = 0;
    #pragma unroll
    for (int j = 0; j < 14; ++j)
      if (v[j] > bv){ bv = v[j]; bj = j; }
    int bi = t + bj * 256;
    #pragma unroll
    for (int m = 1; m < 64; m <<= 1){
      float ov = __shfl_xor(bv, m);
      int   oi = __shfl_xor(bi, m);
      if (ov > bv || (ov == bv && oi < bi)){ bv = ov; bi = oi; }
    }
    if (l == 0){ wv[wid] = bv; wi[wid] = bi; }
    __syncthreads();
    float gv = wv[0]; int gi = wi[0];
    #pragma unroll
    for (int k = 1; k < 4; ++k){
      float ov = wv[k]; int oi = wi[k];
      if (ov > gv || (ov == gv && oi < gi)){ gv = ov; gi = oi; }
    }
    if (t == 0) idx[b * TOPK_ + it] = gi;
    // owner clears its slot (static unrolled indexing -> stays in registers)
    const int ot = gi & 255, oj = gi >> 8;
    #pragma unroll
    for (int j = 0; j < 14; ++j)
      if (t == ot && j == oj) v[j] = -3.0e38f;
    __syncthreads();
  }
}

__global__ __launch_bounds__(256)
void centroid_part(const float* __restrict__ mlps, const int* __restrict__ y,
                   const float* __restrict__ cnt, float* __restrict__ part){
  __shared__ float acc[C_ * 256];
  __shared__ float winv[C_];
  const int t  = threadIdx.x;
  const int ob = blockIdx.x * 256;
  const int e  = blockIdx.y;
  const int s  = blockIdx.z;
  #pragma unroll
  for (int c = 0; c < C_; ++c) acc[c * 256 + t] = 0.f;
  if (t < C_) winv[t] = 1.f / (cnt[t] + 1e-12f);
  __syncthreads();
  const int n0 = s * 425, n1 = n0 + 425;
  for (int n = n0; n < n1; ++n){
    int c = y[n];
    float v = mlps[((long)e * N_ + n) * D2_ + ob + t];
    acc[c * 256 + t] += winv[c] * v;
  }
  #pragma unroll
  for (int c = 0; c < C_; ++c)
    part[(((long)s * E_ + e) * C_ + c) * D2_ + ob + t] = acc[c * 256 + t];
}

__global__ __launch_bounds__(256)
void centroid_reduce(const float* __restrict__ part, float* __restrict__ cent){
  int i = blockIdx.x * 256 + threadIdx.x;
  if (i >= E_ * C_ * D2_) return;
  float s = 0.f;
  #pragma unroll
  for (int k = 0; k < 8; ++k) s += part[(long)k * E_ * C_ * D2_ + i];
  cent[i] = s;
}

__global__ __launch_bounds__(256)
void rownorm_inplace(float* __restrict__ X, int D){
  int r = blockIdx.x, t = threadIdx.x;
  float4* x4 = reinterpret_cast<float4*>(X + (long)r * D);
  float ss = 0.f;
  for (int i = t; i < (D >> 2); i += 256){
    float4 v = x4[i];
    ss += v.x*v.x + v.y*v.y + v.z*v.z + v.w*v.w;
  }
  __shared__ float red[256];
  red[t] = ss; __syncthreads();
  for (int s2 = 128; s2; s2 >>= 1){ if (t < s2) red[t] += red[t + s2]; __syncthreads(); }
  float rinv = 1.f / fmaxf(sqrtf(red[0]), 1e-12f);
  for (int i = t; i < (D >> 2); i += 256){
    float4 v = x4[i];
    v.x *= rinv; v.y *= rinv; v.z *= rinv; v.w *= rinv;
    x4[i] = v;
  }
}

// per (e,row): 17 cosine dots with cn; mode 1 -> softmax, mode 0 -> TAU*cos
// 4 waves/block, one row per wave
__global__ __launch_bounds__(256)
void ens_dot(const float* __restrict__ mlp, const float* __restrict__ cn,
             float* __restrict__ out, int mlp_rows, int out_M, int out_rowoff, int mode){
  const int wv = threadIdx.x >> 6, l = threadIdx.x & 63;
  const int row = blockIdx.x * 4 + wv, e = blockIdx.y;
  if (row >= mlp_rows) return;
  const float4* r4 = reinterpret_cast<const float4*>(mlp + ((long)e * mlp_rows + row) * D2_);
  float4 r[4];
  #pragma unroll
  for (int j = 0; j < 4; ++j) r[j] = r4[j * 64 + l];
  float ss = 0.f;
  #pragma unroll
  for (int j = 0; j < 4; ++j) ss += r[j].x*r[j].x + r[j].y*r[j].y + r[j].z*r[j].z + r[j].w*r[j].w;
  ss = wsum64(ss);
  float rinv = 1.f / fmaxf(sqrtf(ss), 1e-12f);
  float tv[C_];
  #pragma unroll
  for (int c = 0; c < C_; ++c){
    const float4* c4 = reinterpret_cast<const float4*>(cn + ((long)e * C_ + c) * D2_);
    float p = 0.f;
    #pragma unroll
    for (int j = 0; j < 4; ++j){
      float4 cv = c4[j * 64 + l];
      p += r[j].x*cv.x + r[j].y*cv.y + r[j].z*cv.z + r[j].w*cv.w;
    }
    tv[c] = wsum64(p) * rinv * TAU_;
  }
  long obase = ((long)e * out_M + out_rowoff + row) * C_;
  if (mode == 0){
    if (l == 0){
      #pragma unroll
      for (int c = 0; c < C_; ++c) out[obase + c] = tv[c];
    }
  } else {
    float m = tv[0];
    #pragma unroll
    for (int c = 1; c < C_; ++c) m = fmaxf(m, tv[c]);
    float p[C_]; float sum = 0.f;
    #pragma unroll
    for (int c = 0; c < C_; ++c){ p[c] = expf(tv[c] - m); sum += p[c]; }
    float is = 1.f / sum;
    if (l == 0){
      #pragma unroll
      for (int c = 0; c < C_; ++c) out[obase + c] = p[c] * is;
    }
  }
}

__global__ __launch_bounds__(256)
void outputs_k(const float* __restrict__ soft, const int* __restrict__ idx, float* __restrict__ out){
  const int lane = threadIdx.x & 63;
  const int b = blockIdx.x * 4 + (threadIdx.x >> 6);
  const int* id = idx + b * TOPK_;
  float o = 0.f;
  for (int e = 0; e < E_; ++e){
    float S = 0.f;
    const float* se = soft + (long)e * N_ * C_;
    #pragma unroll
    for (int k = 0; k < TOPK_; ++k){
      int n = id[k];
      if (lane < C_) S += se[(long)n * C_ + lane];
    }
    float tot = wsum64(S);
    o += S / (tot + 1e-12f);
  }
  if (lane < C_) out[(long)b * C_ + lane] = o * (1.f / E_);
}

extern "C" void kernel_launch(void* const* d_in, const int* in_sizes, int n_in,
                              void* d_out, int out_size, void* d_ws, size_t ws_size,
                              hipStream_t stream){
  const float* z        = (const float*)d_in[0];
  const float* supports = (const float*)d_in[1];
  const float* labels   = (const float*)d_in[2];
  const float* weight   = (const float*)d_in[3];
  const float* alpha    = (const float*)d_in[4];
  const float* gamma    = (const float*)d_in[5];
  const float* bias     = (const float*)d_in[6];
  float* out = (float*)d_out;

  char* w = (char*)d_ws;
  size_t off = 0;
  auto alloc = [&](size_t bytes)->char*{
    char* p = w + off;
    off = (off + bytes + 255) & ~(size_t)255;
    return p;
  };
  auto rup = [](size_t b)->size_t{ return (b + 255) & ~(size_t)255; };

  // ---- permanent region (~82 MB) ----
  float* zinv   = (float*)alloc((size_t)B_ * 4);
  float* sinv   = (float*)alloc((size_t)N_ * 4);
  float* cnt    = (float*)alloc((size_t)C_ * 4);
  int*   y      = (int*)  alloc((size_t)N_ * 4);
  int*   idx    = (int*)  alloc((size_t)B_ * TOPK_ * 4);
  unsigned short* zh  = (unsigned short*)alloc((size_t)B_  * D1_ * 2);
  unsigned short* sh  = (unsigned short*)alloc((size_t)NP_ * D1_ * 2);
  unsigned short* wbf = (unsigned short*)alloc((size_t)NE_ * D1_ * 2);
  float* cent = (float*)alloc((size_t)E_ * C_ * D2_ * 4);
  float* part = (float*)alloc((size_t)8 * E_ * C_ * D2_ * 4);
  float* soft = (float*)alloc((size_t)E_ * N_ * C_ * 4);

  // ---- overlay region: lifetimes do not overlap (≈139 MB) ----
  // phase 1 (scores+topk): scores | zl | sl      (86.7 MB)
  // phase 2 (mlp_s..soft): mlps                  (139.3 MB)
  // phase 3 (logits):      mlpz 2048-row chunks  (83.9 MB, aliases mlps)
  const size_t scores_b = (size_t)B_ * N_ * 4;
  const size_t zl_b     = (size_t)B_  * D1_ * 2;
  const size_t sl_b     = (size_t)NP_ * D1_ * 2;
  const size_t mlps_b   = (size_t)E_ * N_ * D2_ * 4;
  size_t ph1 = rup(scores_b) + rup(zl_b) + rup(sl_b);
  char* overlay = alloc(ph1 > mlps_b ? ph1 : mlps_b);
  float*          scores = (float*)overlay;
  unsigned short* zl     = (unsigned short*)(overlay + rup(scores_b));
  unsigned short* sl     = (unsigned short*)(overlay + rup(scores_b) + rup(zl_b));
  float*          mlps   = (float*)overlay;          // after topk20
  float*          mlpz   = (float*)overlay;          // after ens_dot(soft)
  (void)ws_size; (void)in_sizes; (void)n_in; (void)out_size;

  // row norms + label prep
  rownorm_inv<<<B_, 256, 0, stream>>>(z, D1_, zinv);
  rownorm_inv<<<N_, 256, 0, stream>>>(supports, D1_, sinv);
  zero_cnt<<<1, 32, 0, stream>>>(cnt);
  labelprep<<<(N_ + 255) / 256, 256, 0, stream>>>(labels, y, cnt);

  // bf16 precompute: hi/lo splits (hi doubles as the mlp A operand), pad, folded W
  cvt_split<<<(B_ * D1_ / 4 + 255) / 256, 256, 0, stream>>>(z, zh, zl, (long)B_ * D1_ / 4);
  cvt_split<<<(N_ * D1_ / 4 + 255) / 256, 256, 0, stream>>>(supports, sh, sl, (long)N_ * D1_ / 4);
  fill_pad<<<(NP_ - N_) * D1_ / 8 / 256, 256, 0, stream>>>(sh, sl);
  wfold<<<(int)((long)NE_ * D1_ / 4 / 256), 256, 0, stream>>>(weight, alpha, wbf);

  // cosine scores (split-bf16 3-term, fp32-faithful for top-k) + top-20
  mfma_scores2<<<dim3(NP_ / 128, B_ / 128, 1), 256, 0, stream>>>(
      zh, zl, sh, sl, zinv, sinv, scores);
  topk20<<<B_, 256, 0, stream>>>(scores, idx);
  // (scores, zl, sl dead from here)

  // mlp_s: single fused GEMM over N' = E*D2 columns
  mfma_be<<<dim3(NE_ / 128, NP_ / 128, 1), 256, 0, stream>>>(
      sh, wbf, gamma, bias, mlps, (long)N_ * D2_, N_);

  // centroids, then L2-normalize rows
  centroid_part<<<dim3(D2_ / 256, E_, 8), 256, 0, stream>>>(mlps, y, cnt, part);
  centroid_reduce<<<(E_ * C_ * D2_ + 255) / 256, 256, 0, stream>>>(part, cent);
  rownorm_inplace<<<E_ * C_, 256, 0, stream>>>(cent, D2_);

  // soft = softmax(TAU * cos(mlp_s, cent))
  ens_dot<<<dim3((N_ + 3) / 4, E_), 256, 0, stream>>>(mlps, cent, soft, N_, N_, 0, 1);

  // outputs
  outputs_k<<<B_ / 4, 256, 0, stream>>>(soft, idx, out);
  // (mlps dead from here; mlpz reuses its space)

  // logits, 2 chunks of 2048 z rows
  float* logits = out + (size_t)B_ * C_;
  for (int ch = 0; ch < 2; ++ch){
    mfma_be<<<dim3(NE_ / 128, 2048 / 128, 1), 256, 0, stream>>>(
        zh + (size_t)ch * 2048 * D1_, wbf, gamma, bias, mlpz, (long)2048 * D2_, 2048);
    ens_dot<<<dim3(2048 / 4, E_), 256, 0, stream>>>(mlpz, cent, logits, 2048, B_, ch * 2048, 0);
  }
}